// Round 15
// baseline (86.153 us; speedup 1.0000x reference)
//
#include <hip/hip_runtime.h>

#define HH 8
#define LL 4
#define PP 2
#define DD 32
#define CC 256
#define NVV 21760
#define NQQ 1000
#define BB 4
#define NQT (BB * NQQ)   // 4000 total queries
#define QB 4             // queries per sample_agg_proj block

typedef __attribute__((ext_vector_type(8))) short short8;
typedef __attribute__((ext_vector_type(4))) short shortv4;
typedef __attribute__((ext_vector_type(4))) float f32x4;

__device__ __forceinline__ unsigned short f2bf(float f) {
    unsigned u = __float_as_uint(f);
    u += 0x7FFF + ((u >> 16) & 1);  // round-to-nearest-even
    return (unsigned short)(u >> 16);
}
__device__ __forceinline__ float bf2f(unsigned short h) {
    return __uint_as_float(((unsigned)h) << 16);
}

// ---------------------------------------------------------------------------
// Kernel 0: weight prep. Block c (=k row, 0..255), thread n. Coalesced reads.
//  WT[n][c]  = bf16(W_val[c][n])   ([n][k] row-major — proj B operand)
//  W1T[n][c] = bf16([W_off|W_attn][c][n]),  WoT[n][c] = bf16(W_out[c][n])
// ---------------------------------------------------------------------------
__global__ __launch_bounds__(256) void prep_kernel(
    const float* __restrict__ Wv, const float* __restrict__ Woff,
    const float* __restrict__ Wattn, const float* __restrict__ Wout,
    unsigned short* __restrict__ WT, unsigned short* __restrict__ W1T,
    unsigned short* __restrict__ WoT)
{
    const int c = blockIdx.x;   // k index 0..255
    const int n = threadIdx.x;  // output col 0..255
    WT[n * CC + c] = f2bf(Wv[c * CC + n]);
    if (n < 192) {
        float x = (n < 128) ? Woff[c * 128 + n] : Wattn[c * 64 + (n - 128)];
        W1T[n * CC + c] = f2bf(x);
    }
    WoT[n * CC + c] = f2bf(Wout[c * CC + n]);
}

// ---------------------------------------------------------------------------
// Kernel 1: logits[4000,192] = query @ [W_off|W_attn] + bias.
// BM=32, BK=64 (4 iters), 4 waves x 48 cols. Padded LDS rows (72).
// ---------------------------------------------------------------------------
__global__ __launch_bounds__(256) void logits_mfma(
    const float* __restrict__ query, const unsigned short* __restrict__ W1T,
    const float* __restrict__ b_off, const float* __restrict__ b_attn,
    float* __restrict__ logits)
{
    __shared__ unsigned short As[32][72];
    __shared__ unsigned short Bsl[192][72];
    const int tid = threadIdx.x;
    const int lane = tid & 63;
    const int wave = tid >> 6;
    const int bm = blockIdx.x * 32;  // 125 blocks * 32 = 4000
    const int lr = lane & 15;
    const int q = lane >> 4;
    f32x4 acc[2][3] = {};

    for (int k0 = 0; k0 < CC; k0 += 64) {
        float4 a[2];
        short8 wv[6];
#pragma unroll
        for (int i = 0; i < 2; ++i) {
            int u = tid + 256 * i;  // 512 float4 units: row=u>>4, col4=(u&15)*4
            a[i] = *(const float4*)&query[(size_t)(bm + (u >> 4)) * CC + k0 +
                                          (u & 15) * 4];
        }
#pragma unroll
        for (int i = 0; i < 6; ++i) {
            int u = tid + 256 * i;  // 1536 16B units: n=u>>3, j=u&7
            wv[i] = *(const short8*)&W1T[(size_t)(u >> 3) * CC + k0 + (u & 7) * 8];
        }
        __syncthreads();
#pragma unroll
        for (int i = 0; i < 2; ++i) {
            int u = tid + 256 * i;
            shortv4 p;
            p[0] = (short)f2bf(a[i].x); p[1] = (short)f2bf(a[i].y);
            p[2] = (short)f2bf(a[i].z); p[3] = (short)f2bf(a[i].w);
            *(shortv4*)&As[u >> 4][(u & 15) * 4] = p;
        }
#pragma unroll
        for (int i = 0; i < 6; ++i) {
            int u = tid + 256 * i;
            *(short8*)&Bsl[u >> 3][(u & 7) * 8] = wv[i];
        }
        __syncthreads();

#pragma unroll
        for (int kk = 0; kk < 2; ++kk) {
            short8 afr[2], bfr[3];
#pragma unroll
            for (int mf = 0; mf < 2; ++mf)
                afr[mf] = *(const short8*)&As[mf * 16 + lr][kk * 32 + q * 8];
#pragma unroll
            for (int nf = 0; nf < 3; ++nf)
                bfr[nf] =
                    *(const short8*)&Bsl[wave * 48 + nf * 16 + lr][kk * 32 + q * 8];
#pragma unroll
            for (int mf = 0; mf < 2; ++mf)
#pragma unroll
                for (int nf = 0; nf < 3; ++nf)
                    acc[mf][nf] = __builtin_amdgcn_mfma_f32_16x16x32_bf16(
                        afr[mf], bfr[nf], acc[mf][nf], 0, 0, 0);
        }
        __syncthreads();
    }

#pragma unroll
    for (int nf = 0; nf < 3; ++nf) {
        int col = wave * 48 + nf * 16 + lr;
        float bias = (col < 128) ? b_off[col] : b_attn[col - 128];
#pragma unroll
        for (int mf = 0; mf < 2; ++mf)
#pragma unroll
            for (int r = 0; r < 4; ++r) {
                int m = bm + mf * 16 + q * 4 + r;
                logits[(size_t)m * 192 + col] = acc[mf][nf][r] + bias;
            }
    }
}

// ---------------------------------------------------------------------------
// Kernel 2: sample_agg_proj — the algebraic reorder. For QB=4 queries:
//   agg[q][h][0:256] = sum_{l,p,corners} attn*w*valid * value[b, idx, :]
//   wsum[q][h]       = sum attn*w*valid
//   mid[q][h*32+d]   = agg[q][h] . WT[h*32+d] + wsum[q][h]*b_val[h*32+d]
// Gathers RAW fp32 value rows (1KB, coalesced across 64 lanes); agg is
// exact fp32. Replaces the 47us valproj GEMM + v write + sample read.
// 1000 blocks x 256 thr; wave w handles heads {w, w+4}; LDS ~35.5KB.
// ---------------------------------------------------------------------------
__global__ __launch_bounds__(256) void sample_agg_proj(
    const float* __restrict__ logits,   // [4000][192]
    const float* __restrict__ refp,     // [B,NQ,L,2]
    const float* __restrict__ value,    // [B,NV,256] fp32 (raw input)
    const unsigned short* __restrict__ WT,  // [n][k] bf16
    const float* __restrict__ b_val,
    unsigned short* __restrict__ mid)   // [4000][256] bf16
{
    __shared__ float offl[QB][128];
    __shared__ float attnl[QB][64];
    __shared__ float refl[QB][8];
    __shared__ float agg[QB * 8 * 256];   // 32 KB
    __shared__ float wsum[QB][8];

    const int bq0 = blockIdx.x * QB;   // NQQ % QB == 0 -> same b for all 4
    const int b = bq0 / NQQ;
    const int tid = threadIdx.x;
    const int lane = tid & 63;
    const int w = tid >> 6;

#pragma unroll
    for (int qi = 0; qi < QB; ++qi) {
        if (tid < 192) {
            float t = logits[(size_t)(bq0 + qi) * 192 + tid];
            if (tid < 128) offl[qi][tid] = t;
            else attnl[qi][tid - 128] = t;
        }
    }
    if (tid < QB * 8) refl[tid >> 3][tid & 7] = refp[(size_t)bq0 * 8 + tid];
    __syncthreads();

    if (tid < QB * 8) {  // softmax per (qi, h)
        int qi = tid >> 3, h = tid & 7;
        float m = -1e30f;
#pragma unroll
        for (int j = 0; j < 8; ++j) m = fmaxf(m, attnl[qi][h * 8 + j]);
        float s = 0.f, e[8];
#pragma unroll
        for (int j = 0; j < 8; ++j) {
            e[j] = __expf(attnl[qi][h * 8 + j] - m);
            s += e[j];
        }
        float inv = 1.f / s;
#pragma unroll
        for (int j = 0; j < 8; ++j) attnl[qi][h * 8 + j] = e[j] * inv;
    }
    __syncthreads();

    const int starts[4] = {0, 16384, 20480, 21504};
    const float szs[4] = {128.f, 64.f, 32.f, 16.f};

#pragma unroll
    for (int qi = 0; qi < QB; ++qi) {
#pragma unroll
        for (int hh = 0; hh < 2; ++hh) {
            const int h = w + hh * 4;
            f32x4 acc = {0.f, 0.f, 0.f, 0.f};
            float ws = 0.f;
#pragma unroll
            for (int l = 0; l < LL; ++l) {
                const float S = szs[l];
                const int Wl = (int)S;
                const float refx = refl[qi][l * 2 + 0];
                const float refy = refl[qi][l * 2 + 1];
                const float* vbase =
                    value + (size_t)(b * NVV + starts[l]) * 256 + (lane << 2);
#pragma unroll
                for (int p = 0; p < PP; ++p) {
                    const int oi = h * 16 + l * 4 + p * 2;
                    float lx = refx + offl[qi][oi + 0] / S;
                    float ly = refy + offl[qi][oi + 1] / S;
                    float x = lx * S - 0.5f;
                    float y = ly * S - 0.5f;
                    float x0f = floorf(x), y0f = floorf(y);
                    float fx = x - x0f, fy = y - y0f;
                    int x0 = (int)x0f, y0 = (int)y0f;
                    float a = attnl[qi][h * 8 + l * 2 + p];
#pragma unroll
                    for (int dy = 0; dy < 2; ++dy) {
#pragma unroll
                        for (int dx = 0; dx < 2; ++dx) {
                            int xi = x0 + dx, yi = y0 + dy;
                            float wgt =
                                (dx ? fx : 1.f - fx) * (dy ? fy : 1.f - fy);
                            bool valid = (xi >= 0) && (xi < Wl) &&
                                         (yi >= 0) && (yi < Wl);
                            int xc = min(max(xi, 0), Wl - 1);
                            int yc = min(max(yi, 0), Wl - 1);
                            float cw = valid ? a * wgt : 0.f;
                            f32x4 g = *(const f32x4*)(vbase +
                                                      (size_t)(yc * Wl + xc) *
                                                          256);
                            acc[0] += cw * g[0];
                            acc[1] += cw * g[1];
                            acc[2] += cw * g[2];
                            acc[3] += cw * g[3];
                            ws += cw;
                        }
                    }
                }
            }
            *(f32x4*)&agg[((qi << 3) + h) * 256 + (lane << 2)] = acc;
            if (lane == 0) wsum[qi][h] = ws;
        }
    }
    __syncthreads();

    // ---- projection: thread = output col n; dot(agg, WT-row) ----
    {
        const int n = tid;
        const int h = n >> 5;
        const unsigned short* wrow = WT + (size_t)n * CC;
        float accm[QB] = {0.f, 0.f, 0.f, 0.f};
#pragma unroll 4
        for (int c0 = 0; c0 < CC; c0 += 8) {
            short8 wv8 = *(const short8*)&wrow[c0];
#pragma unroll
            for (int j = 0; j < 8; ++j) {
                float wv = bf2f((unsigned short)wv8[j]);
                int c = c0 + j;
#pragma unroll
                for (int qi = 0; qi < QB; ++qi)
                    accm[qi] += agg[((qi << 3) + h) * 256 + c] * wv;
            }
        }
        float bn = b_val[n];
#pragma unroll
        for (int qi = 0; qi < QB; ++qi)
            mid[(size_t)(bq0 + qi) * CC + n] =
                f2bf(accm[qi] + wsum[qi][h] * bn);
    }
}

// ---------------------------------------------------------------------------
// Kernel 3: out[4000,256] = mid_bf16 @ W_out_bf16 + b_out.
// BM=32, BK=64 (4 iters), 4 waves x 64 cols. Padded LDS rows (72).
// ---------------------------------------------------------------------------
__global__ __launch_bounds__(256) void out_mfma(
    const unsigned short* __restrict__ mid,
    const unsigned short* __restrict__ WoT, const float* __restrict__ b_out,
    float* __restrict__ out)
{
    __shared__ unsigned short As[32][72];
    __shared__ unsigned short Bso[256][72];
    const int tid = threadIdx.x;
    const int lane = tid & 63;
    const int wave = tid >> 6;
    const int bm = blockIdx.x * 32;
    const int lr = lane & 15;
    const int q = lane >> 4;
    f32x4 acc[2][4] = {};

    for (int k0 = 0; k0 < CC; k0 += 64) {
        short8 a0 = *(const short8*)&mid[(size_t)(bm + (tid >> 3)) * CC + k0 +
                                         (tid & 7) * 8];
        short8 wv[8];
#pragma unroll
        for (int i = 0; i < 8; ++i) {
            int u = tid + 256 * i;  // 2048 16B units: n=u>>3, j=u&7
            wv[i] = *(const short8*)&WoT[(size_t)(u >> 3) * CC + k0 + (u & 7) * 8];
        }
        __syncthreads();
        *(short8*)&As[tid >> 3][(tid & 7) * 8] = a0;
#pragma unroll
        for (int i = 0; i < 8; ++i) {
            int u = tid + 256 * i;
            *(short8*)&Bso[u >> 3][(u & 7) * 8] = wv[i];
        }
        __syncthreads();

#pragma unroll
        for (int kk = 0; kk < 2; ++kk) {
            short8 afr[2], bfr[4];
#pragma unroll
            for (int mf = 0; mf < 2; ++mf)
                afr[mf] = *(const short8*)&As[mf * 16 + lr][kk * 32 + q * 8];
#pragma unroll
            for (int nf = 0; nf < 4; ++nf)
                bfr[nf] =
                    *(const short8*)&Bso[wave * 64 + nf * 16 + lr][kk * 32 + q * 8];
#pragma unroll
            for (int mf = 0; mf < 2; ++mf)
#pragma unroll
                for (int nf = 0; nf < 4; ++nf)
                    acc[mf][nf] = __builtin_amdgcn_mfma_f32_16x16x32_bf16(
                        afr[mf], bfr[nf], acc[mf][nf], 0, 0, 0);
        }
        __syncthreads();
    }

#pragma unroll
    for (int nf = 0; nf < 4; ++nf) {
        int col = wave * 64 + nf * 16 + lr;
        float bias = b_out[col];
#pragma unroll
        for (int mf = 0; mf < 2; ++mf)
#pragma unroll
            for (int r = 0; r < 4; ++r) {
                int m = bm + mf * 16 + q * 4 + r;
                out[(size_t)m * CC + col] = acc[mf][nf][r] + bias;
            }
    }
}

extern "C" void kernel_launch(void* const* d_in, const int* in_sizes, int n_in,
                              void* d_out, int out_size, void* d_ws, size_t ws_size,
                              hipStream_t stream) {
    const float* query  = (const float*)d_in[0];
    const float* value  = (const float*)d_in[1];
    const float* refp   = (const float*)d_in[2];
    const float* W_off  = (const float*)d_in[3];
    const float* b_off  = (const float*)d_in[4];
    const float* W_attn = (const float*)d_in[5];
    const float* b_attn = (const float*)d_in[6];
    const float* W_val  = (const float*)d_in[7];
    const float* b_val  = (const float*)d_in[8];
    const float* W_out  = (const float*)d_in[9];
    const float* b_out  = (const float*)d_in[10];
    float* out = (float*)d_out;

    char* ws = (char*)d_ws;
    unsigned short* WT     = (unsigned short*)(ws);             // 128 KB
    unsigned short* W1T    = (unsigned short*)(ws + 131072);    // 96 KB
    unsigned short* WoT    = (unsigned short*)(ws + 262144);    // 128 KB
    float*          logits = (float*)(ws + 393216);             // 3 MB
    unsigned short* mid    = (unsigned short*)(ws + 3465216);   // 2 MB

    prep_kernel<<<CC, 256, 0, stream>>>(W_val, W_off, W_attn, W_out,
                                        WT, W1T, WoT);
    logits_mfma<<<NQT / 32, 256, 0, stream>>>(query, W1T, b_off, b_attn, logits);
    sample_agg_proj<<<NQT / QB, 256, 0, stream>>>(logits, refp, value, WT,
                                                  b_val, mid);
    out_mfma<<<NQT / 32, 256, 0, stream>>>(mid, WoT, b_out, out);
}